// Round 4
// baseline (1339.592 us; speedup 1.0000x reference)
//
#include <hip/hip_runtime.h>

typedef __bf16 bf16x8 __attribute__((ext_vector_type(8)));
typedef float floatx4 __attribute__((ext_vector_type(4)));

__device__ __forceinline__ float u2f(unsigned short u) {
  union { unsigned int i; float f; } v; v.i = ((unsigned int)u) << 16; return v.f;
}
__device__ __forceinline__ unsigned short f2b(float f) {
  union { float f; unsigned int i; } v; v.f = f;
  unsigned int r = (v.i + 0x7fffu + ((v.i >> 16) & 1u)) >> 16;
  return (unsigned short)r;
}

__device__ __forceinline__ void gl16(const void* g, void* l) {
  __builtin_amdgcn_global_load_lds(
      (const __attribute__((address_space(1))) unsigned int*)g,
      (__attribute__((address_space(3))) unsigned int*)l, 16, 0, 0);
}

// image sizes (ushort units). FCH/QCH padded to 1280x16B so every thread of a
// 256-thread block issues EXACTLY 5 global_load_lds per chunk -> vmcnt(5) is
// exact for every wave (old 2256/1104-unit images gave wave 3 one fewer load
// than the vmcnt assumed -> latent under-wait race).
#define FCH 10240   // ffn chunk: W1c[32x136]@0, W2c[128x40]@4352, b1c(32 f32)@9472
#define QCH 10240   // qkv chunk: W[64x136]@0, bias(64 f32)@8704
#define OCH 18176   // wo: W[128x136]@0, bo@17408, g@17664, b@17920 (128 f32 each)

// ---------------------------------------------------------------------------
// Generic GEMM (final projections only): C = A[M,K](bf16) @ W[N,K](f32)^T + b
// mode 1: relu->bf16; mode 2: heads epilogue (fp32, 8 t-steps)
// ---------------------------------------------------------------------------
#define LDS_STRIDE 48

__global__ __launch_bounds__(256) void gemm_kernel(
    const unsigned short* __restrict__ A, int lda,
    const float* __restrict__ W, int ldw,
    const float* __restrict__ bias,
    unsigned short* __restrict__ outB, float* __restrict__ outF,
    int M, int N, int K, int ldc, int mode)
{
  __shared__ unsigned short As[128 * LDS_STRIDE];
  __shared__ unsigned short Bs[128 * LDS_STRIDE];

  const int tid  = threadIdx.x;
  const int m0   = blockIdx.y * 128;
  const int n0   = blockIdx.x * 128;
  const int wave = tid >> 6;
  const int lane = tid & 63;
  const int wm   = (wave >> 1) * 64;
  const int wn   = (wave & 1) * 64;
  const int lr   = lane & 15;
  const int lq   = lane >> 4;

  floatx4 acc[4][4];
#pragma unroll
  for (int i = 0; i < 4; i++)
#pragma unroll
    for (int j = 0; j < 4; j++)
      acc[i][j] = (floatx4){0.f, 0.f, 0.f, 0.f};

  for (int k0 = 0; k0 < K; k0 += 32) {
    __syncthreads();
#pragma unroll
    for (int i = 0; i < 2; i++) {
      int c   = tid + i * 256;
      int row = c >> 2;
      int k8  = (c & 3) * 8;
      uint4 val = {0u, 0u, 0u, 0u};
      if (m0 + row < M)
        val = *(const uint4*)(A + (size_t)(m0 + row) * lda + k0 + k8);
      *(uint4*)(&As[row * LDS_STRIDE + k8]) = val;
    }
#pragma unroll
    for (int i = 0; i < 4; i++) {
      int c   = tid + i * 256;
      int row = c >> 3;
      int k4  = (c & 7) * 4;
      float f0 = 0.f, f1 = 0.f, f2 = 0.f, f3 = 0.f;
      if (n0 + row < N) {
        const float* p = W + (size_t)(n0 + row) * ldw + k0 + k4;
        f0 = p[0]; f1 = p[1]; f2 = p[2]; f3 = p[3];
      }
      ushort4 pk;
      pk.x = f2b(f0); pk.y = f2b(f1); pk.z = f2b(f2); pk.w = f2b(f3);
      *(ushort4*)(&Bs[row * LDS_STRIDE + k4]) = pk;
    }
    __syncthreads();

    bf16x8 af[4], bfr[4];
#pragma unroll
    for (int t = 0; t < 4; t++) {
      af[t]  = *(const bf16x8*)(&As[(wm + t * 16 + lr) * LDS_STRIDE + lq * 8]);
      bfr[t] = *(const bf16x8*)(&Bs[(wn + t * 16 + lr) * LDS_STRIDE + lq * 8]);
    }
#pragma unroll
    for (int tm = 0; tm < 4; tm++)
#pragma unroll
      for (int tn = 0; tn < 4; tn++)
        acc[tm][tn] = __builtin_amdgcn_mfma_f32_16x16x32_bf16(
            af[tm], bfr[tn], acc[tm][tn], 0, 0, 0);
  }

#pragma unroll
  for (int tm = 0; tm < 4; tm++) {
#pragma unroll
    for (int tn = 0; tn < 4; tn++) {
      int gcol = n0 + wn + tn * 16 + lr;
      if (gcol >= N) continue;
      float bs = bias[gcol];
      if (mode == 2) {
        float wl = W[(size_t)gcol * ldw + K];
#pragma unroll
        for (int r = 0; r < 4; r++) {
          int grow = m0 + wm + tm * 16 + lq * 4 + r;
          float base = acc[tm][tn][r] + bs;
          float* op = outF + ((size_t)grow * 8) * (size_t)N + gcol;
#pragma unroll
          for (int t = 0; t < 8; t++)
            op[(size_t)t * N] = base + (float)t * wl;
        }
      } else {
#pragma unroll
        for (int r = 0; r < 4; r++) {
          int grow = m0 + wm + tm * 16 + lq * 4 + r;
          if (grow < M) {
            float v = acc[tm][tn][r] + bs;
            if (mode == 1) v = fmaxf(v, 0.f);
            outB[(size_t)grow * ldc + gcol] = f2b(v);
          }
        }
      }
    }
  }
}

// ---------------------------------------------------------------------------
// MFMA attention: one block per (b,h). S=200, hd=16.
// v4: no bulk LDS zeroing. K-pad cols 16..31 of q/k written as zeros inline
// with staging; only tail rows (200..207) and V/P pad cols get tiny loops.
// ---------------------------------------------------------------------------
#define QKSTR 40
#define PSTR  232

__global__ __launch_bounds__(256) void attn_kernel(
    const unsigned short* __restrict__ qkv, unsigned short* __restrict__ out)
{
  __shared__ __attribute__((aligned(16))) unsigned short qsh[208 * QKSTR];
  __shared__ __attribute__((aligned(16))) unsigned short ksh[208 * QKSTR];
  __shared__ __attribute__((aligned(16))) unsigned short vsh[16 * PSTR];
  __shared__ __attribute__((aligned(16))) unsigned short psh[4][16 * PSTR];

  const int bh   = blockIdx.x;
  const int b    = bh >> 3, h = bh & 7;
  const int tid  = threadIdx.x;
  const int wave = tid >> 6;
  const int lane = tid & 63;
  const int lr   = lane & 15;
  const int lq   = lane >> 4;
  const size_t rowbase = (size_t)b * 200;

  // tail rows 200..207, cols 0..31 of q/k (chunk 12 reads them)
  {
    int rem = tid & 127;
    int row = 200 + (rem >> 4);
    int col = (rem & 15) * 2;
    unsigned int* dst = (tid < 128) ? (unsigned int*)&qsh[row * QKSTR + col]
                                    : (unsigned int*)&ksh[row * QKSTR + col];
    *dst = 0u;
  }
  // vsh pad cols 200..231
  {
    int row = tid >> 4, col = 200 + (tid & 15) * 2;
    *(unsigned int*)&vsh[row * PSTR + col] = 0u;
  }
  // psh pad cols 208..223 (PV reads up to col 223), all 4 wave buffers
  for (int u = tid; u < 512; u += 256) {
    int w = u >> 7, rem = u & 127;
    int row = rem >> 3, col = 208 + (rem & 7) * 2;
    *(unsigned int*)&psh[w][row * PSTR + col] = 0u;
  }

  // stage q,k row-major [s][0..16) + zero cols 16..31; v transposed [d][s]
  const uint2 z2 = {0u, 0u};
  for (int i = tid; i < 800; i += 256) {
    int s = i >> 2, d4 = (i & 3) * 4;
    const unsigned short* base = qkv + (rowbase + s) * 384 + h * 16 + d4;
    uint2 qv = *(const uint2*)(base);
    uint2 kv = *(const uint2*)(base + 128);
    uint2 vv = *(const uint2*)(base + 256);
    *(uint2*)&qsh[s * QKSTR + d4] = qv;
    *(uint2*)&ksh[s * QKSTR + d4] = kv;
    *(uint2*)&qsh[s * QKSTR + 16 + d4] = z2;
    *(uint2*)&ksh[s * QKSTR + 16 + d4] = z2;
    vsh[(d4 + 0) * PSTR + s] = (unsigned short)(vv.x & 0xffffu);
    vsh[(d4 + 1) * PSTR + s] = (unsigned short)(vv.x >> 16);
    vsh[(d4 + 2) * PSTR + s] = (unsigned short)(vv.y & 0xffffu);
    vsh[(d4 + 3) * PSTR + s] = (unsigned short)(vv.y >> 16);
  }
  __syncthreads();

  unsigned short* pw = &psh[wave][0];

  for (int t = wave; t < 13; t += 4) {
    const int q0 = t * 16;
    bf16x8 qf = *(const bf16x8*)&qsh[(q0 + lr) * QKSTR + lq * 8];

    floatx4 s[13];
#pragma unroll
    for (int c = 0; c < 13; c++) {
      bf16x8 kf = *(const bf16x8*)&ksh[(c * 16 + lr) * QKSTR + lq * 8];
      s[c] = __builtin_amdgcn_mfma_f32_16x16x32_bf16(
          qf, kf, (floatx4){0.f, 0.f, 0.f, 0.f}, 0, 0, 0);
    }

    float mx[4] = {-1e30f, -1e30f, -1e30f, -1e30f};
#pragma unroll
    for (int c = 0; c < 13; c++)
#pragma unroll
      for (int r = 0; r < 4; r++) {
        float v = s[c][r] * 0.25f;
        if (c == 12 && lr >= 8) v = -1e30f;
        s[c][r] = v;
        mx[r] = fmaxf(mx[r], v);
      }
#pragma unroll
    for (int m = 1; m < 16; m <<= 1)
#pragma unroll
      for (int r = 0; r < 4; r++)
        mx[r] = fmaxf(mx[r], __shfl_xor(mx[r], m, 16));

    float sm[4] = {0.f, 0.f, 0.f, 0.f};
#pragma unroll
    for (int c = 0; c < 13; c++)
#pragma unroll
      for (int r = 0; r < 4; r++) {
        float e = __expf(s[c][r] - mx[r]);
        s[c][r] = e;
        sm[r] += e;
      }
#pragma unroll
    for (int m = 1; m < 16; m <<= 1)
#pragma unroll
      for (int r = 0; r < 4; r++)
        sm[r] += __shfl_xor(sm[r], m, 16);

#pragma unroll
    for (int c = 0; c < 13; c++)
#pragma unroll
      for (int r = 0; r < 4; r++)
        pw[(lq * 4 + r) * PSTR + c * 16 + lr] = f2b(s[c][r]);

    floatx4 o = {0.f, 0.f, 0.f, 0.f};
#pragma unroll
    for (int ks = 0; ks < 7; ks++) {
      bf16x8 pf = *(const bf16x8*)&pw[lr * PSTR + ks * 32 + lq * 8];
      bf16x8 vf = *(const bf16x8*)&vsh[lr * PSTR + ks * 32 + lq * 8];
      o = __builtin_amdgcn_mfma_f32_16x16x32_bf16(pf, vf, o, 0, 0, 0);
    }

#pragma unroll
    for (int r = 0; r < 4; r++) {
      int q = q0 + lq * 4 + r;
      if (q < 200)
        out[(rowbase + q) * 128 + h * 16 + lr] = f2b(o[r] / sm[r]);
    }
  }
}

// ---------------------------------------------------------------------------
// Weight prepack: bf16 LDS images (chunk-contiguous, strides baked in).
// grid 284: [0,256) ffn (pi*64+c, 32 mid-cols each), [256,280) qkv (pi*6+c),
// [280,284) wo (pi)
// ---------------------------------------------------------------------------
__global__ __launch_bounds__(256) void prep_kernel(
    const float* __restrict__ W1, const float* __restrict__ b1,
    const float* __restrict__ W2,
    const float* __restrict__ Wqkv, const float* __restrict__ bqkv,
    const float* __restrict__ Wo, const float* __restrict__ bo,
    const float* __restrict__ ln1g, const float* __restrict__ ln1b,
    unsigned short* __restrict__ fimg, unsigned short* __restrict__ qimg,
    unsigned short* __restrict__ oimg)
{
  const int blk = blockIdx.x;
  const int tid = threadIdx.x;
  if (blk < 256) {
    const int pi = blk >> 6, c = blk & 63;
    unsigned short* o = fimg + (size_t)blk * FCH;
    const float* w1 = W1 + ((size_t)pi * 2048 + c * 32) * 128;
    const float* w2 = W2 + (size_t)pi * 128 * 2048 + c * 32;
    // W1c: 32 rows x 128 cols, stride 136 (pad cols 128..135)
    for (int u = tid; u < 32 * 34; u += 256) {
      int row = u / 34, c4 = (u % 34) * 4;
      ushort4 pk = {0, 0, 0, 0};
      if (c4 < 128) {
        const float* p = w1 + row * 128 + c4;
        pk.x = f2b(p[0]); pk.y = f2b(p[1]); pk.z = f2b(p[2]); pk.w = f2b(p[3]);
      }
      *(ushort4*)&o[row * 136 + c4] = pk;
    }
    // W2c: 128 rows x 32 cols, stride 40 (pad cols 32..39)
    for (int u = tid; u < 128 * 10; u += 256) {
      int row = u / 10, c4 = (u % 10) * 4;
      ushort4 pk = {0, 0, 0, 0};
      if (c4 < 32) {
        const float* p = w2 + (size_t)row * 2048 + c4;
        pk.x = f2b(p[0]); pk.y = f2b(p[1]); pk.z = f2b(p[2]); pk.w = f2b(p[3]);
      }
      *(ushort4*)&o[4352 + row * 40 + c4] = pk;
    }
    if (tid < 32)
      ((float*)(o + 9472))[tid] = b1[(size_t)pi * 2048 + c * 32 + tid];
  } else if (blk < 280) {
    const int q = blk - 256;
    const int pi = q / 6, c = q % 6;
    unsigned short* o = qimg + (size_t)q * QCH;
    const float* w = Wqkv + ((size_t)pi * 384 + c * 64) * 128;
    for (int u = tid; u < 64 * 34; u += 256) {
      int row = u / 34, c4 = (u % 34) * 4;
      ushort4 pk = {0, 0, 0, 0};
      if (c4 < 128) {
        const float* p = w + row * 128 + c4;
        pk.x = f2b(p[0]); pk.y = f2b(p[1]); pk.z = f2b(p[2]); pk.w = f2b(p[3]);
      }
      *(ushort4*)&o[row * 136 + c4] = pk;
    }
    if (tid < 64)
      ((float*)(o + 8704))[tid] = bqkv[(size_t)pi * 384 + c * 64 + tid];
  } else {
    const int pi = blk - 280;
    unsigned short* o = oimg + (size_t)pi * OCH;
    const float* w = Wo + (size_t)pi * 128 * 128;
    for (int u = tid; u < 128 * 34; u += 256) {
      int row = u / 34, c4 = (u % 34) * 4;
      ushort4 pk = {0, 0, 0, 0};
      if (c4 < 128) {
        const float* p = w + row * 128 + c4;
        pk.x = f2b(p[0]); pk.y = f2b(p[1]); pk.z = f2b(p[2]); pk.w = f2b(p[3]);
      }
      *(ushort4*)&o[row * 136 + c4] = pk;
    }
    if (tid < 128) {
      ((float*)(o + 17408))[tid] = bo[(size_t)pi * 128 + tid];
      ((float*)(o + 17664))[tid] = ln1g[(size_t)pi * 128 + tid];
      ((float*)(o + 17920))[tid] = ln1b[(size_t)pi * 128 + tid];
    }
  }
}

// ---------------------------------------------------------------------------
// QKV: out[25600,384] = x[25600,128] @ Wqkv^T + bqkv (bf16 out)
// 64-row tiles (grid 400), 6 N-chunks of 64, double-buffered gl16,
// exactly 5 loads/thread/chunk -> vmcnt(5). 40 KB LDS -> 4 blocks/CU.
// ---------------------------------------------------------------------------
__global__ __launch_bounds__(256) void qkv_kernel(
    const unsigned short* __restrict__ x,
    const unsigned short* __restrict__ wimg,   // 6 * QCH
    unsigned short* __restrict__ out)
{
  __shared__ __attribute__((aligned(16))) unsigned short wbuf[2][QCH];

  const int tid  = threadIdx.x;
  const int wave = tid >> 6;
  const int lane = tid & 63;
  const int lr   = lane & 15;
  const int lq   = lane >> 4;
  const int m0   = blockIdx.x * 64;
  const int wm   = wave * 16;

  bf16x8 af[4];
#pragma unroll
  for (int ks = 0; ks < 4; ks++)
    af[ks] = *(const bf16x8*)(x + (size_t)(m0 + wm + lr) * 128 + ks * 32 + lq * 8);

#pragma unroll
  for (int i = 0; i < 5; i++) {
    int u = tid + i * 256;
    gl16(wimg + (size_t)u * 8, &wbuf[0][(size_t)u * 8]);
  }

  for (int c = 0; c < 6; c++) {
    if (c + 1 < 6) {
      const unsigned short* src = wimg + (size_t)(c + 1) * QCH;
      unsigned short* dst = &wbuf[(c + 1) & 1][0];
#pragma unroll
      for (int i = 0; i < 5; i++) {
        int u = tid + i * 256;
        gl16(src + (size_t)u * 8, dst + (size_t)u * 8);
      }
      asm volatile("s_waitcnt vmcnt(5)" ::: "memory");
    } else {
      asm volatile("s_waitcnt vmcnt(0)" ::: "memory");
    }
    __builtin_amdgcn_s_barrier();
    __builtin_amdgcn_sched_barrier(0);

    const unsigned short* wb = &wbuf[c & 1][0];

    floatx4 acc[4];
#pragma unroll
    for (int tn = 0; tn < 4; tn++) acc[tn] = (floatx4){0.f, 0.f, 0.f, 0.f};
#pragma unroll
    for (int ks = 0; ks < 4; ks++)
#pragma unroll
      for (int tn = 0; tn < 4; tn++) {
        bf16x8 wf = *(const bf16x8*)&wb[(tn * 16 + lr) * 136 + ks * 32 + lq * 8];
        acc[tn] = __builtin_amdgcn_mfma_f32_16x16x32_bf16(af[ks], wf, acc[tn], 0, 0, 0);
      }
    const float* bc = (const float*)(wb + 8704);
#pragma unroll
    for (int tn = 0; tn < 4; tn++) {
      float bb = bc[tn * 16 + lr];
#pragma unroll
      for (int r = 0; r < 4; r++) {
        int row = m0 + wm + lq * 4 + r;
        out[(size_t)row * 384 + c * 64 + tn * 16 + lr] = f2b(acc[tn][r] + bb);
      }
    }
    __builtin_amdgcn_s_barrier();
  }
}

// ---------------------------------------------------------------------------
// Wo + residual + LN1 fused: x = LN(x + attn @ Wo^T + bo) * g + b
// ---------------------------------------------------------------------------
__global__ __launch_bounds__(256) void wo_ln_kernel(
    const unsigned short* __restrict__ attn,
    const unsigned short* __restrict__ wimg,   // OCH
    unsigned short* __restrict__ x)
{
  __shared__ __attribute__((aligned(16))) unsigned short wbuf[OCH];

  const int tid  = threadIdx.x;
  const int wave = tid >> 6;
  const int lane = tid & 63;
  const int lr   = lane & 15;
  const int lq   = lane >> 4;
  const int m0   = blockIdx.x * 64;
  const int wm   = wave * 16;

#pragma unroll
  for (int i = 0; i < 9; i++) {
    int u = tid + i * 256;
    if (u < 2272) gl16(wimg + (size_t)u * 8, &wbuf[(size_t)u * 8]);
  }

  bf16x8 af[4];
#pragma unroll
  for (int ks = 0; ks < 4; ks++)
    af[ks] = *(const bf16x8*)(attn + (size_t)(m0 + wm + lr) * 128 + ks * 32 + lq * 8);

  asm volatile("s_waitcnt vmcnt(0)" ::: "memory");
  __builtin_amdgcn_s_barrier();
  __builtin_amdgcn_sched_barrier(0);

  floatx4 acc[8];
#pragma unroll
  for (int i = 0; i < 8; i++) acc[i] = (floatx4){0.f, 0.f, 0.f, 0.f};
#pragma unroll
  for (int ks = 0; ks < 4; ks++)
#pragma unroll
    for (int tn = 0; tn < 8; tn++) {
      bf16x8 wf = *(const bf16x8*)&wbuf[(tn * 16 + lr) * 136 + ks * 32 + lq * 8];
      acc[tn] = __builtin_amdgcn_mfma_f32_16x16x32_bf16(af[ks], wf, acc[tn], 0, 0, 0);
    }

  const float* bo = (const float*)(wbuf + 17408);
  const float* g  = (const float*)(wbuf + 17664);
  const float* bb = (const float*)(wbuf + 17920);

  float v[8][4];
  float s[4] = {0.f, 0.f, 0.f, 0.f}, ss[4] = {0.f, 0.f, 0.f, 0.f};
#pragma unroll
  for (int tn = 0; tn < 8; tn++) {
    float bsv = bo[tn * 16 + lr];
#pragma unroll
    for (int r = 0; r < 4; r++) {
      size_t idx = (size_t)(m0 + wm + lq * 4 + r) * 128 + tn * 16 + lr;
      float t = acc[tn][r] + bsv + u2f(x[idx]);
      v[tn][r] = t;
      s[r] += t;
      ss[r] += t * t;
    }
  }
#pragma unroll
  for (int m = 1; m < 16; m <<= 1)
#pragma unroll
    for (int r = 0; r < 4; r++) {
      s[r]  += __shfl_xor(s[r], m, 16);
      ss[r] += __shfl_xor(ss[r], m, 16);
    }
  float mean[4], rstd[4];
#pragma unroll
  for (int r = 0; r < 4; r++) {
    mean[r] = s[r] * (1.f / 128.f);
    float var = ss[r] * (1.f / 128.f) - mean[r] * mean[r];
    rstd[r] = rsqrtf(var + 1e-5f);
  }
#pragma unroll
  for (int tn = 0; tn < 8; tn++) {
    int col = tn * 16 + lr;
    float gv = g[col], bv = bb[col];
#pragma unroll
    for (int r = 0; r < 4; r++) {
      size_t idx = (size_t)(m0 + wm + lq * 4 + r) * 128 + col;
      x[idx] = f2b((v[tn][r] - mean[r]) * rstd[r] * gv + bv);
    }
  }
}

// ---------------------------------------------------------------------------
// Fused FFN + residual + LN2: x = LN(x + ffn(x)) * g + b   (in place)
// v3: 64 chunks of 32 mid-cols, exactly 5 gl16/thread/chunk -> vmcnt(5)
// exact; 46 KB LDS -> 3 blocks/CU (all 400 blocks co-resident).
// ---------------------------------------------------------------------------
__global__ __launch_bounds__(256) void ffn_kernel(
    const unsigned short* __restrict__ xin,
    const unsigned short* __restrict__ wimg,   // 64 * FCH
    const float* __restrict__ b2,
    const float* __restrict__ g2, const float* __restrict__ bb2,
    unsigned short* __restrict__ x)
{
  __shared__ __attribute__((aligned(16))) unsigned short wbuf[2][FCH];
  __shared__ __attribute__((aligned(16))) unsigned short mids[64 * 40];

  const int tid  = threadIdx.x;
  const int wave = tid >> 6;
  const int lane = tid & 63;
  const int lr   = lane & 15;
  const int lq   = lane >> 4;
  const int m0   = blockIdx.x * 64;
  const int wm   = wave * 16;

  bf16x8 af[4];
#pragma unroll
  for (int ks = 0; ks < 4; ks++)
    af[ks] = *(const bf16x8*)(xin + (size_t)(m0 + wm + lr) * 128 + ks * 32 + lq * 8);

  floatx4 acc[8];
#pragma unroll
  for (int i = 0; i < 8; i++) acc[i] = (floatx4){0.f, 0.f, 0.f, 0.f};

#pragma unroll
  for (int i = 0; i < 5; i++) {
    int u = tid + i * 256;
    gl16(wimg + (size_t)u * 8, &wbuf[0][(size_t)u * 8]);
  }

  for (int c = 0; c < 64; c++) {
    if (c + 1 < 64) {
      const unsigned short* src = wimg + (size_t)(c + 1) * FCH;
      unsigned short* dst = &wbuf[(c + 1) & 1][0];
#pragma unroll
      for (int i = 0; i < 5; i++) {
        int u = tid + i * 256;
        gl16(src + (size_t)u * 8, dst + (size_t)u * 8);
      }
      asm volatile("s_waitcnt vmcnt(5)" ::: "memory");
    } else {
      asm volatile("s_waitcnt vmcnt(0)" ::: "memory");
    }
    __builtin_amdgcn_s_barrier();
    __builtin_amdgcn_sched_barrier(0);

    const unsigned short* wb = &wbuf[c & 1][0];

    // FFN1: mid[wm..wm+16][0..32) = relu(x @ W1c^T + b1c)
    floatx4 macc[2];
#pragma unroll
    for (int tn = 0; tn < 2; tn++) macc[tn] = (floatx4){0.f, 0.f, 0.f, 0.f};
#pragma unroll
    for (int ks = 0; ks < 4; ks++)
#pragma unroll
      for (int tn = 0; tn < 2; tn++) {
        bf16x8 wf = *(const bf16x8*)&wb[(tn * 16 + lr) * 136 + ks * 32 + lq * 8];
        macc[tn] = __builtin_amdgcn_mfma_f32_16x16x32_bf16(af[ks], wf, macc[tn], 0, 0, 0);
      }
    const float* b1c = (const float*)(wb + 9472);
#pragma unroll
    for (int tn = 0; tn < 2; tn++) {
      float bb = b1c[tn * 16 + lr];
#pragma unroll
      for (int r = 0; r < 4; r++) {
        float v = fmaxf(macc[tn][r] + bb, 0.f);
        mids[(wm + lq * 4 + r) * 40 + tn * 16 + lr] = f2b(v);
      }
    }
    // FFN2 accumulate (wave-private mid rows), K = 32 -> single k-step
    {
      bf16x8 mf = *(const bf16x8*)&mids[(wm + lr) * 40 + lq * 8];
#pragma unroll
      for (int tn = 0; tn < 8; tn++) {
        bf16x8 wf = *(const bf16x8*)&wb[4352 + (tn * 16 + lr) * 40 + lq * 8];
        acc[tn] = __builtin_amdgcn_mfma_f32_16x16x32_bf16(mf, wf, acc[tn], 0, 0, 0);
      }
    }
    __builtin_amdgcn_s_barrier();
  }

  // epilogue: residual + LN2, write x
  float v[8][4];
  float s[4] = {0.f, 0.f, 0.f, 0.f}, ss[4] = {0.f, 0.f, 0.f, 0.f};
#pragma unroll
  for (int tn = 0; tn < 8; tn++) {
    float bsv = b2[tn * 16 + lr];
#pragma unroll
    for (int r = 0; r < 4; r++) {
      size_t idx = (size_t)(m0 + wm + lq * 4 + r) * 128 + tn * 16 + lr;
      float t = acc[tn][r] + bsv + u2f(x[idx]);
      v[tn][r] = t;
      s[r] += t;
      ss[r] += t * t;
    }
  }
#pragma unroll
  for (int m = 1; m < 16; m <<= 1)
#pragma unroll
    for (int r = 0; r < 4; r++) {
      s[r]  += __shfl_xor(s[r], m, 16);
      ss[r] += __shfl_xor(ss[r], m, 16);
    }
  float mean[4], rstd[4];
#pragma unroll
  for (int r = 0; r < 4; r++) {
    mean[r] = s[r] * (1.f / 128.f);
    float var = ss[r] * (1.f / 128.f) - mean[r] * mean[r];
    rstd[r] = rsqrtf(var + 1e-5f);
  }
#pragma unroll
  for (int tn = 0; tn < 8; tn++) {
    int col = tn * 16 + lr;
    float gv = g2[col], bv = bb2[col];
#pragma unroll
    for (int r = 0; r < 4; r++) {
      size_t idx = (size_t)(m0 + wm + lq * 4 + r) * 128 + col;
      x[idx] = f2b((v[tn][r] - mean[r]) * rstd[r] * gv + bv);
    }
  }
}

// ---------------------------------------------------------------------------
__global__ __launch_bounds__(256) void gather_kernel(
    const int* __restrict__ ids, const float* __restrict__ table,
    unsigned short* __restrict__ x)
{
  int t0 = blockIdx.x * 256 + threadIdx.x;
#pragma unroll
  for (int i = 0; i < 4; i++) {
    int u = t0 + i * 409600;
    int row = u >> 6, dp = (u & 63) << 1;
    int id = ids[row];
    const float* p = table + (size_t)id * 128 + dp;
    float f0 = p[0], f1 = p[1];
    ((unsigned int*)x)[u] = (unsigned int)f2b(f0) | ((unsigned int)f2b(f1) << 16);
  }
}

__global__ __launch_bounds__(512) void pool_kernel(
    const unsigned short* __restrict__ x, unsigned short* __restrict__ hcat,
    int col0)
{
  __shared__ float part[512];
  int b = blockIdx.x;
  int d = threadIdx.x & 127;
  int g = threadIdx.x >> 7;
  float s = 0.f;
  for (int t = 0; t < 50; t++)
    s += u2f(x[(size_t)(b * 200 + g * 50 + t) * 128 + d]);
  part[threadIdx.x] = s;
  __syncthreads();
  if (g == 0) {
    float tot = part[d] + part[d + 128] + part[d + 256] + part[d + 384];
    hcat[b * 256 + col0 + d] = f2b(tot * (1.f / 200.f));
  }
}

// ---------------------------------------------------------------------------
static void gemm(hipStream_t st, const unsigned short* A, int lda,
                 const float* W, int ldw, const float* bias,
                 unsigned short* outB, float* outF,
                 int M, int N, int K, int ldc, int mode)
{
  dim3 grid((N + 127) / 128, (M + 127) / 128);
  gemm_kernel<<<grid, dim3(256), 0, st>>>(A, lda, W, ldw, bias, outB, outF,
                                          M, N, K, ldc, mode);
}

extern "C" void kernel_launch(void* const* d_in, const int* in_sizes, int n_in,
                              void* d_out, int out_size, void* d_ws, size_t ws_size,
                              hipStream_t stream)
{
  const int*   tab_ids     = (const int*)d_in[0];
  const int*   idx_ids     = (const int*)d_in[1];
  const float* table_embed = (const float*)d_in[2];
  const float* idx_embed   = (const float*)d_in[3];
  const float* Wqkv = (const float*)d_in[4];
  const float* bqkv = (const float*)d_in[5];
  const float* Wo   = (const float*)d_in[6];
  const float* bo   = (const float*)d_in[7];
  const float* ln1g = (const float*)d_in[8];
  const float* ln1b = (const float*)d_in[9];
  const float* W1   = (const float*)d_in[10];
  const float* b1   = (const float*)d_in[11];
  const float* W2   = (const float*)d_in[12];
  const float* b2   = (const float*)d_in[13];
  const float* ln2g = (const float*)d_in[14];
  const float* ln2b = (const float*)d_in[15];
  const float* Wlin = (const float*)d_in[16];
  const float* blin = (const float*)d_in[17];
  const float* Wtab = (const float*)d_in[18];
  const float* btab = (const float*)d_in[19];
  const float* Widx = (const float*)d_in[20];
  const float* bidx = (const float*)d_in[21];
  float* out = (float*)d_out;
  char*  ws  = (char*)d_ws;

  const size_t off_x    = 0;                 // 25600*128 bf16
  const size_t off_qkv  = 6553600;           // 25600*384 bf16
  const size_t off_attn = 26214400;          // 25600*128 bf16
  const size_t off_hcat = 32768000;          // 128*256 bf16
  const size_t off_h    = off_hcat + 65536;  // 128*512 bf16
  const size_t off_fimg = 33030144;          // 256 * FCH * 2 = 5,242,880
  const size_t off_qimg = off_fimg + (size_t)256 * FCH * 2;   // 24 * QCH * 2
  const size_t off_oimg = off_qimg + (size_t)24 * QCH * 2;    // 4 * OCH * 2

  unsigned short* x    = (unsigned short*)(ws + off_x);
  unsigned short* qkv  = (unsigned short*)(ws + off_qkv);
  unsigned short* attn = (unsigned short*)(ws + off_attn);
  unsigned short* hcat = (unsigned short*)(ws + off_hcat);
  unsigned short* h    = (unsigned short*)(ws + off_h);
  unsigned short* fimg = (unsigned short*)(ws + off_fimg);
  unsigned short* qimg = (unsigned short*)(ws + off_qimg);
  unsigned short* oimg = (unsigned short*)(ws + off_oimg);

  prep_kernel<<<284, 256, 0, stream>>>(W1, b1, W2, Wqkv, bqkv, Wo, bo,
                                       ln1g, ln1b, fimg, qimg, oimg);

  for (int e = 0; e < 2; e++) {
    gather_kernel<<<1600, 256, 0, stream>>>(
        e == 0 ? tab_ids : idx_ids,
        e == 0 ? table_embed : idx_embed, x);
    for (int l = 0; l < 2; l++) {
      int pi = e * 2 + l;
      qkv_kernel<<<400, 256, 0, stream>>>(x, qimg + (size_t)pi * 6 * QCH, qkv);
      attn_kernel<<<1024, 256, 0, stream>>>(qkv, attn);
      wo_ln_kernel<<<400, 256, 0, stream>>>(attn, oimg + (size_t)pi * OCH, x);
      ffn_kernel<<<400, 256, 0, stream>>>(
          x, fimg + (size_t)pi * 64 * FCH, b2 + pi * 128,
          ln2g + pi * 128, ln2b + pi * 128, x);
    }
    pool_kernel<<<128, 512, 0, stream>>>(x, hcat, e * 128);
  }

  gemm(stream, hcat, 256, Wlin, 256, blin, h, nullptr, 128, 512, 256, 512, 1);
  gemm(stream, h, 512, Wtab, 513, btab, nullptr, out,           128, 1000,   512, 1000,   2);
  gemm(stream, h, 512, Widx, 513, bidx, nullptr, out + 1024000, 128, 100000, 512, 100000, 2);
}